// Round 7
// baseline (6851.002 us; speedup 1.0000x reference)
//
#include <hip/hip_runtime.h>
#include <math.h>

#define NN 512
#define BB 32
#define TT 12
#define HH 12
#define UU 64
#define CAP 128
#define RTOT (NN * BB)          // 16384 rows

__device__ __forceinline__ float sigm(float x) { return 1.f / (1.f + expf(-x)); }

// ---------------- ELL build: int2 {idx, val_bits} at [p*1024 + s*512 + row] -----
__global__ __launch_bounds__(256) void build_ell(const float* __restrict__ sup,
                                                 int2* __restrict__ ell,
                                                 int* __restrict__ ecnt) {
    int wave = (blockIdx.x * blockDim.x + threadIdx.x) >> 6;
    int lane = threadIdx.x & 63;
    if (wave >= 2 * NN) return;
    const float* row = sup + (size_t)wave * NN;
    int base = 0;
    for (int k = 0; k < NN / 64; ++k) {
        float v = row[k * 64 + lane];
        unsigned long long m = __ballot(v != 0.0f);
        int pre = __popcll(m & ((1ull << lane) - 1ull));
        if (v != 0.0f) {
            int pos = base + pre;
            if (pos < CAP)
                ell[(size_t)pos * 1024 + wave] = make_int2(k * 64 + lane, __float_as_int(v));
        }
        base += __popcll(m);
    }
    if (lane == 0) ecnt[wave] = base < CAP ? base : CAP;
}

__global__ void zero_kernel(float* __restrict__ p, int n) {
    int i = blockIdx.x * 256 + threadIdx.x;
    if (i < n) p[i] = 0.0f;
}

// ---------------- dense GEMM: Zm = X0_h @ Wm (h-channels only; x via combine) ---
// A gathered from h (layouts [b][u][n]); double-buffered LDS, 1 barrier/k-tile.
// Z layout (W-blocked): Z[((m*32+b)*(OO/WZ) + og)*512*WZ + n*WZ + oi]
template<bool L0, bool GATED, int OO>
__global__ __launch_bounds__(256) void gemm_f(const float* __restrict__ hA,
                                              const float* __restrict__ hB,
                                              const float* __restrict__ g,
                                              const float* __restrict__ W,
                                              float* __restrict__ Z) {
    constexpr int C  = L0 ? 64 : 128;
    constexpr int KT = C / 32;           // 2 or 4
    constexpr int WZ = (OO == 128) ? 8 : 4;
    constexpr int JW = OO / 16;          // o's per thread (8 or 4)
    constexpr int NW = OO / 32;          // W float4 loads per thread

    __shared__ float  At[2][32][68];
    __shared__ float4 Ws[2][32][OO / 4];

    int b  = blockIdx.x >> 3;
    int n0 = (blockIdx.x & 7) * 64;
    int m  = blockIdx.y;
    int tid = threadIdx.x, tx = tid & 15, ty = tid >> 4;

    float acc[4][JW];
    #pragma unroll
    for (int i = 0; i < 4; ++i)
        #pragma unroll
        for (int j = 0; j < JW; ++j) acc[i][j] = 0.f;

    float  va[8];
    float4 vw[NW];

    auto loadAB = [&](int kt) {
        #pragma unroll
        for (int i = 0; i < 8; ++i) {
            int p = i * 256 + tid;
            int rr = p & 63, kk = p >> 6;
            int c = kt * 32 + kk;
            int nn = n0 + rr;
            float v;
            if (L0) {
                v = hA[(size_t)((b << 6) + c) * 512 + nn];
                if (GATED) v *= g[(size_t)((b << 7) + c) * 512 + nn];
            } else {
                if (c < 64) {
                    v = hA[(size_t)((b << 6) + c) * 512 + nn];
                } else {
                    int u = c - 64;
                    v = hB[(size_t)((b << 6) + u) * 512 + nn];
                    if (GATED) v *= g[(size_t)((b << 7) + u) * 512 + nn];
                }
            }
            va[i] = v;
        }
        #pragma unroll
        for (int i = 0; i < NW; ++i) {
            int p = i * 256 + tid;
            int o4 = p & (OO / 4 - 1);
            int kk = p / (OO / 4);
            int c = kt * 32 + kk;
            int crow = L0 ? (c + 1) : c;     // original W row (x occupies row 0 for L0)
            vw[i] = *(const float4*)&W[(size_t)(crow * 5 + m) * OO + o4 * 4];
        }
    };
    auto stash = [&](int buf) {
        #pragma unroll
        for (int i = 0; i < 8; ++i) {
            int p = i * 256 + tid;
            At[buf][p >> 6][p & 63] = va[i];
        }
        #pragma unroll
        for (int i = 0; i < NW; ++i) {
            int p = i * 256 + tid;
            int o4 = p & (OO / 4 - 1);
            int kk = p / (OO / 4);
            if (OO == 128) Ws[buf][kk][(o4 & 1) * 16 + (o4 >> 1)] = vw[i];
            else           Ws[buf][kk][o4] = vw[i];
        }
    };

    loadAB(0);
    stash(0);
    __syncthreads();
    for (int kt = 0; kt < KT; ++kt) {
        int cur = kt & 1;
        if (kt + 1 < KT) loadAB(kt + 1);      // prefetch hides under FMA
        #pragma unroll 8
        for (int kk = 0; kk < 32; ++kk) {
            float4 a = *(float4*)&At[cur][kk][ty * 4];
            float av[4] = {a.x, a.y, a.z, a.w};
            float4 w0 = Ws[cur][kk][tx];
            if (OO == 128) {
                float4 w1 = Ws[cur][kk][tx + 16];
                #pragma unroll
                for (int i = 0; i < 4; ++i) {
                    acc[i][0] += av[i] * w0.x; acc[i][1] += av[i] * w0.y;
                    acc[i][2] += av[i] * w0.z; acc[i][3] += av[i] * w0.w;
                    acc[i][4] += av[i] * w1.x; acc[i][5] += av[i] * w1.y;
                    acc[i][6] += av[i] * w1.z; acc[i][7] += av[i] * w1.w;
                }
            } else {
                #pragma unroll
                for (int i = 0; i < 4; ++i) {
                    acc[i][0] += av[i] * w0.x; acc[i][1] += av[i] * w0.y;
                    acc[i][2] += av[i] * w0.z; acc[i][3] += av[i] * w0.w;
                }
            }
        }
        if (kt + 1 < KT) stash(cur ^ 1);
        __syncthreads();
    }

    float* Zt = Z + ((size_t)(m * 32 + b) * (OO / WZ) + tx) * (512 * WZ);
    #pragma unroll
    for (int i = 0; i < 4; ++i) {
        int nn = n0 + ty * 4 + i;
        *(float4*)&Zt[nn * WZ] = make_float4(acc[i][0], acc[i][1], acc[i][2], acc[i][3]);
        if (OO == 128)
            *(float4*)&Zt[nn * WZ + 4] = make_float4(acc[i][4], acc[i][5], acc[i][6], acc[i][7]);
    }
}

// ---------------- combine: out = Z0 - Z2 - Z4 + S1(Z1+2S1Z2) + S2(Z3+2S2Z4) -----
// HX: Zm's are missing the rank-1 x-term -> add x[b][n] * Wx[m][o] at read time.
// MODE 0: gate -> g = sigmoid(out + bg)        (OO=128, W=8)
// MODE 1: cand -> h = u*h + (1-u)*tanh(out+bc) (OO=64,  W=4), u from gin
template<int MODE, bool HX>
__global__ __launch_bounds__(512) void combine(const float* __restrict__ Z,
                                               const int2* __restrict__ ell,
                                               const int* __restrict__ ecnt,
                                               const float* __restrict__ bias,
                                               const float* __restrict__ xv,
                                               const float* __restrict__ Wx,
                                               float* __restrict__ gout,
                                               const float* __restrict__ gin,
                                               float* __restrict__ h) {
    constexpr int W  = (MODE == 0) ? 8 : 4;
    constexpr int OO = (MODE == 0) ? 128 : 64;
    constexpr size_t TILE = (size_t)512 * W;
    const size_t MS = (size_t)32 * (OO / W) * TILE;   // per-m stride = RTOT*OO

    __shared__ float Ta[512 * W];
    __shared__ float Tb[512 * W];

    int b  = blockIdx.x >> 4;
    int o0 = (blockIdx.x & 15) * W;
    int n  = threadIdx.x;
    const float* Zt = Z + ((size_t)b * (OO / W) + (o0 / W)) * TILE;

    int cnt0 = ecnt[n], cnt1 = ecnt[NN + n];

    float xw[5][W];
    float xn = 0.f;
    if (HX) {
        #pragma unroll
        for (int m = 0; m < 5; ++m)
            #pragma unroll
            for (int fi = 0; fi < W; ++fi)
                xw[m][fi] = Wx[(size_t)m * OO + o0 + fi];
        xn = xv[b * 512 + n];
    }

    auto stage = [&](float* T, int m) {
        const float4* src = (const float4*)(Zt + m * MS);
        if (W == 8) {
            #pragma unroll
            for (int i = 0; i < 2; ++i) {
                int f4 = i * 512 + n;
                int row = f4 >> 1, half = f4 & 1;
                float4 v = src[f4];
                if (HX) {
                    float xr = xv[b * 512 + row];
                    v.x += xr * xw[m][half * 4 + 0]; v.y += xr * xw[m][half * 4 + 1];
                    v.z += xr * xw[m][half * 4 + 2]; v.w += xr * xw[m][half * 4 + 3];
                }
                *(float4*)&T[row * 8 + ((half ^ row) & 1) * 4] = v;
            }
        } else {
            float4 v = src[n];
            if (HX) {
                v.x += xn * xw[m][0]; v.y += xn * xw[m][1];
                v.z += xn * xw[m][2]; v.w += xn * xw[m][3];
            }
            *(float4*)&T[n * 4] = v;
        }
    };
    auto own_lds = [&](const float* T, float* o) {
        if (W == 8) {
            *(float4*)&o[0] = *(const float4*)&T[n * 8 + (n & 1) * 4];
            *(float4*)&o[4] = *(const float4*)&T[n * 8 + ((n & 1) ^ 1) * 4];
        } else {
            *(float4*)&o[0] = *(const float4*)&T[n * 4];
        }
    };
    auto own_glob = [&](int m, float* o) {
        const float* src = Zt + m * MS + (size_t)n * W;
        #pragma unroll
        for (int fi = 0; fi < W; ++fi) {
            o[fi] = src[fi];
            if (HX) o[fi] += xn * xw[m][fi];
        }
    };
    auto put_own = [&](float* T, const float* y) {
        if (W == 8) {
            *(float4*)&T[n * 8 + (n & 1) * 4]       = *(const float4*)&y[0];
            *(float4*)&T[n * 8 + ((n & 1) ^ 1) * 4] = *(const float4*)&y[4];
        } else {
            *(float4*)&T[n * 4] = *(const float4*)&y[0];
        }
    };
    auto gather = [&](const float* T, int s, float* o) {
        int cnt = s ? cnt1 : cnt0;
        const int2* e0 = ell + s * NN + n;
        float4 a0 = make_float4(0.f, 0.f, 0.f, 0.f);
        float4 a1 = make_float4(0.f, 0.f, 0.f, 0.f);
        for (int p = 0; p < cnt; ++p) {
            int2 e = e0[(size_t)p << 10];
            int j = e.x;
            float v = __int_as_float(e.y);
            if (W == 8) {
                float4 x0 = *(const float4*)&T[j * 8 + (j & 1) * 4];
                float4 x1 = *(const float4*)&T[j * 8 + ((j & 1) ^ 1) * 4];
                a0.x += v * x0.x; a0.y += v * x0.y; a0.z += v * x0.z; a0.w += v * x0.w;
                a1.x += v * x1.x; a1.y += v * x1.y; a1.z += v * x1.z; a1.w += v * x1.w;
            } else {
                float4 x0 = *(const float4*)&T[j * 4];
                a0.x += v * x0.x; a0.y += v * x0.y; a0.z += v * x0.z; a0.w += v * x0.w;
            }
        }
        *(float4*)&o[0] = a0;
        if (W == 8) *(float4*)&o[4] = a1;
    };

    float z2own[W], z4own[W], y[W], g2[W], g4[W], t1[W];

    stage(Ta, 2);                       // Z2
    __syncthreads();
    own_lds(Ta, z2own);
    gather(Ta, 0, t1);                  // S1 Z2
    own_glob(1, y);                     // Z1
    #pragma unroll
    for (int fi = 0; fi < W; ++fi) y[fi] += 2.f * t1[fi];
    __syncthreads();
    put_own(Tb, y);
    __syncthreads();
    gather(Tb, 0, g2);                  // S1 (Z1 + 2 S1 Z2)
    __syncthreads();
    stage(Ta, 4);                       // Z4
    own_glob(3, y);                     // Z3
    __syncthreads();
    own_lds(Ta, z4own);
    gather(Ta, 1, t1);                  // S2 Z4
    #pragma unroll
    for (int fi = 0; fi < W; ++fi) y[fi] += 2.f * t1[fi];
    __syncthreads();
    put_own(Tb, y);
    __syncthreads();
    gather(Tb, 1, g4);                  // S2 (Z3 + 2 S2 Z4)
    own_glob(0, t1);                    // Z0

    #pragma unroll
    for (int fi = 0; fi < W; ++fi) {
        float acc = t1[fi] - z2own[fi] - z4own[fi] + g2[fi] + g4[fi] + bias[o0 + fi];
        if (MODE == 0) {
            gout[(size_t)((b << 7) + o0 + fi) * 512 + n] = sigm(acc);
        } else {
            float u  = gin[(size_t)((b << 7) + 64 + o0 + fi) * 512 + n];
            float* hp = &h[(size_t)((b << 6) + o0 + fi) * 512 + n];
            float cv = tanhf(acc);
            *hp = u * (*hp) + (1.f - u) * cv;
        }
    }
}

// ---------------- projection ----------------------------------------------------
__global__ void proj_kernel(const float* __restrict__ h1, const float* __restrict__ pW,
                            const float* __restrict__ pb, float* __restrict__ outt) {
    int r = blockIdx.x * 256 + threadIdx.x;
    if (r >= RTOT) return;
    int b = r >> 9, n = r & 511;
    float acc = pb[0];
    #pragma unroll 16
    for (int u = 0; u < 64; ++u)
        acc += h1[(size_t)((b << 6) + u) * 512 + n] * pW[u];
    outt[b * NN + n] = acc;
}

// ================================================================================
extern "C" void kernel_launch(void* const* d_in, const int* in_sizes, int n_in,
                              void* d_out, int out_size, void* d_ws, size_t ws_size,
                              hipStream_t stream) {
    const float* inputs   = (const float*)d_in[0];
    const float* supports = (const float*)d_in[1];
    const float* enc0_Wg = (const float*)d_in[2];
    const float* enc0_bg = (const float*)d_in[3];
    const float* enc0_Wc = (const float*)d_in[4];
    const float* enc0_bc = (const float*)d_in[5];
    const float* enc1_Wg = (const float*)d_in[6];
    const float* enc1_bg = (const float*)d_in[7];
    const float* enc1_Wc = (const float*)d_in[8];
    const float* enc1_bc = (const float*)d_in[9];
    const float* dec0_Wg = (const float*)d_in[10];
    const float* dec0_bg = (const float*)d_in[11];
    const float* dec0_Wc = (const float*)d_in[12];
    const float* dec0_bc = (const float*)d_in[13];
    const float* dec1_Wg = (const float*)d_in[14];
    const float* dec1_bg = (const float*)d_in[15];
    const float* dec1_Wc = (const float*)d_in[16];
    const float* dec1_bc = (const float*)d_in[17];
    const float* projW   = (const float*)d_in[18];
    const float* projb   = (const float*)d_in[19];
    float* out = (float*)d_out;

    char* wsb = (char*)d_ws;
    size_t off = 0;
    auto alloc = [&](size_t bytes) -> char* {
        char* p = wsb + off;
        off = (off + bytes + 255) & ~(size_t)255;
        return p;
    };
    int2*  ell   = (int2*)alloc((size_t)CAP * 1024 * 8);
    int*   ecnt  = (int*)alloc((size_t)2 * NN * 4);
    float* h0    = (float*)alloc((size_t)RTOT * UU * 4);     // [b][u][n]
    float* h1    = (float*)alloc((size_t)RTOT * UU * 4);
    float* xzero = (float*)alloc((size_t)RTOT * 4);
    float* g     = (float*)alloc((size_t)RTOT * 128 * 4);    // [b][go][n]
    float* Z     = (float*)alloc((size_t)5 * RTOT * 128 * 4);
    if (off > ws_size) return;

    build_ell<<<256, 256, 0, stream>>>(supports, ell, ecnt);
    {
        int nz = RTOT * UU * 2 + RTOT;  // h0, h1, xzero contiguous
        zero_kernel<<<(nz + 255) / 256, 256, 0, stream>>>(h0, nz);
    }

    auto cell_l0 = [&](const float* x_bn, float* h, const float* Wgp, const float* bgp,
                       const float* Wcp, const float* bcp) {
        gemm_f<true, false, 128><<<dim3(256, 5), 256, 0, stream>>>(h, nullptr, nullptr, Wgp, Z);
        combine<0, true><<<512, 512, 0, stream>>>(Z, ell, ecnt, bgp, x_bn, Wgp,
                                                  g, nullptr, nullptr);
        gemm_f<true, true, 64><<<dim3(256, 5), 256, 0, stream>>>(h, nullptr, g, Wcp, Z);
        combine<1, true><<<512, 512, 0, stream>>>(Z, ell, ecnt, bcp, x_bn, Wcp,
                                                  nullptr, g, h);
    };
    auto cell_l1 = [&](const float* hin, float* h, const float* Wgp, const float* bgp,
                       const float* Wcp, const float* bcp) {
        gemm_f<false, false, 128><<<dim3(256, 5), 256, 0, stream>>>(hin, h, nullptr, Wgp, Z);
        combine<0, false><<<512, 512, 0, stream>>>(Z, ell, ecnt, bgp, nullptr, nullptr,
                                                   g, nullptr, nullptr);
        gemm_f<false, true, 64><<<dim3(256, 5), 256, 0, stream>>>(hin, h, g, Wcp, Z);
        combine<1, false><<<512, 512, 0, stream>>>(Z, ell, ecnt, bcp, nullptr, nullptr,
                                                   nullptr, g, h);
    };

    for (int t = 0; t < TT; ++t) {
        cell_l0(inputs + (size_t)t * BB * NN, h0, enc0_Wg, enc0_bg, enc0_Wc, enc0_bc);
        cell_l1(h0, h1, enc1_Wg, enc1_bg, enc1_Wc, enc1_bc);
    }
    for (int t = 0; t < HH; ++t) {
        const float* xin = (t == 0) ? xzero : (out + (size_t)(t - 1) * BB * NN);
        cell_l0(xin, h0, dec0_Wg, dec0_bg, dec0_Wc, dec0_bc);
        cell_l1(h0, h1, dec1_Wg, dec1_bg, dec1_Wc, dec1_bc);
        proj_kernel<<<(RTOT + 255) / 256, 256, 0, stream>>>(h1, projW, projb,
                                                            out + (size_t)t * BB * NN);
    }
}

// Round 8
// 6443.707 us; speedup vs baseline: 1.0632x; 1.0632x over previous
//
#include <hip/hip_runtime.h>
#include <math.h>

#define NN 512
#define BB 32
#define TT 12
#define HH 12
#define UU 64
#define CAP 128
#define RTOT (NN * BB)          // 16384 rows

__device__ __forceinline__ float sigm(float x) { return 1.f / (1.f + expf(-x)); }

// ---------------- ELL build: int2 {idx, val_bits} at [p*1024 + s*512 + row] -----
__global__ __launch_bounds__(256) void build_ell(const float* __restrict__ sup,
                                                 int2* __restrict__ ell,
                                                 int* __restrict__ ecnt) {
    int wave = (blockIdx.x * blockDim.x + threadIdx.x) >> 6;
    int lane = threadIdx.x & 63;
    if (wave >= 2 * NN) return;
    const float* row = sup + (size_t)wave * NN;
    int base = 0;
    for (int k = 0; k < NN / 64; ++k) {
        float v = row[k * 64 + lane];
        unsigned long long m = __ballot(v != 0.0f);
        int pre = __popcll(m & ((1ull << lane) - 1ull));
        if (v != 0.0f) {
            int pos = base + pre;
            if (pos < CAP)
                ell[(size_t)pos * 1024 + wave] = make_int2(k * 64 + lane, __float_as_int(v));
        }
        base += __popcll(m);
    }
    if (lane == 0) ecnt[wave] = base < CAP ? base : CAP;
}

__global__ void zero_kernel(float* __restrict__ p, int n) {
    int i = blockIdx.x * 256 + threadIdx.x;
    if (i < n) p[i] = 0.0f;
}

// ---------------- dense GEMM: Zm = X0_h @ Wm (h-channels only; x via combine) ---
// 128n x 64o tile, 256 threads (thread = 8n x 4o), single-buffer LDS + reg
// prefetch. Epilogue passes acc through LDS so global stores are lane-contiguous
// (kills the 2x partial-line write amplification seen in round 7).
// Z layout: gate: Z[m][b][ogZ16][512n][8oi]; cand: Z[m][b][ogZ16][512n][4oi]
template<bool L0, bool GATED, int OO>
__global__ __launch_bounds__(256) void gemm_f(const float* __restrict__ hA,
                                              const float* __restrict__ hB,
                                              const float* __restrict__ g,
                                              const float* __restrict__ W,
                                              float* __restrict__ Z) {
    constexpr int C  = L0 ? 64 : 128;
    constexpr int KT = C / 32;

    __shared__ float At[32][128];   // 16 KB
    __shared__ float Ws[32][68];    // 8.7 KB

    int bx = blockIdx.x;
    int b  = bx >> 2;
    int n0 = (bx & 3) * 128;
    int m  = blockIdx.y;
    int ot = blockIdx.z;                 // o-tile (gate: 0/1, cand: 0)
    int tid = threadIdx.x, tx = tid & 15, ty = tid >> 4;

    float acc[8][4];
    #pragma unroll
    for (int i = 0; i < 8; ++i)
        #pragma unroll
        for (int j = 0; j < 4; ++j) acc[i][j] = 0.f;

    float4 va[4], vw[2];

    auto loadAB = [&](int kt) {
        #pragma unroll
        for (int i = 0; i < 4; ++i) {
            int f4 = i * 256 + tid;
            int c = kt * 32 + (f4 >> 5);
            int nn = n0 + (f4 & 31) * 4;
            float4 v;
            if (L0) {
                v = *(const float4*)&hA[(size_t)((b << 6) + c) * 512 + nn];
                if (GATED) {
                    float4 gv = *(const float4*)&g[(size_t)((b << 7) + c) * 512 + nn];
                    v.x *= gv.x; v.y *= gv.y; v.z *= gv.z; v.w *= gv.w;
                }
            } else {
                if (c < 64) {
                    v = *(const float4*)&hA[(size_t)((b << 6) + c) * 512 + nn];
                } else {
                    int u = c - 64;
                    v = *(const float4*)&hB[(size_t)((b << 6) + u) * 512 + nn];
                    if (GATED) {
                        float4 gv = *(const float4*)&g[(size_t)((b << 7) + u) * 512 + nn];
                        v.x *= gv.x; v.y *= gv.y; v.z *= gv.z; v.w *= gv.w;
                    }
                }
            }
            va[i] = v;
        }
        #pragma unroll
        for (int i = 0; i < 2; ++i) {
            int f4 = i * 256 + tid;
            int kk = f4 >> 4, o4 = f4 & 15;
            int c = kt * 32 + kk;
            int crow = L0 ? (c + 1) : c;      // L0: x occupies original row 0
            vw[i] = *(const float4*)&W[(size_t)(crow * 5 + m) * OO + ot * 64 + o4 * 4];
        }
    };
    auto stash = [&]() {
        #pragma unroll
        for (int i = 0; i < 4; ++i) {
            int f4 = i * 256 + tid;
            *(float4*)&At[f4 >> 5][(f4 & 31) * 4] = va[i];
        }
        #pragma unroll
        for (int i = 0; i < 2; ++i) {
            int f4 = i * 256 + tid;
            *(float4*)&Ws[f4 >> 4][(f4 & 15) * 4] = vw[i];
        }
    };

    loadAB(0);
    for (int kt = 0; kt < KT; ++kt) {
        __syncthreads();               // previous tile fully consumed
        stash();
        __syncthreads();
        if (kt + 1 < KT) loadAB(kt + 1);   // global loads overlap FMA below
        #pragma unroll 8
        for (int kk = 0; kk < 32; ++kk) {
            float4 a0 = *(float4*)&At[kk][ty * 8];
            float4 a1 = *(float4*)&At[kk][ty * 8 + 4];
            float4 w  = *(float4*)&Ws[kk][tx * 4];
            float av[8] = {a0.x, a0.y, a0.z, a0.w, a1.x, a1.y, a1.z, a1.w};
            #pragma unroll
            for (int i = 0; i < 8; ++i) {
                acc[i][0] += av[i] * w.x; acc[i][1] += av[i] * w.y;
                acc[i][2] += av[i] * w.z; acc[i][3] += av[i] * w.w;
            }
        }
    }
    __syncthreads();

    float* lds = &At[0][0];
    if (OO == 128) {
        // gate: ogZ = ot*8 + (tx>>1); oi = (tx&1)*4 + j
        float* ZmB = Z + (size_t)(m * 32 + b) * (16 * 4096);
        #pragma unroll
        for (int p = 0; p < 2; ++p) {
            if ((tx >> 3) == p) {
                int a = (tx >> 1) & 3, hi = (tx & 1) * 4;
                #pragma unroll
                for (int i = 0; i < 8; ++i)
                    *(float4*)&lds[a * 1028 + (ty * 8 + i) * 8 + hi] =
                        make_float4(acc[i][0], acc[i][1], acc[i][2], acc[i][3]);
            }
            __syncthreads();
            #pragma unroll
            for (int j = 0; j < 4; ++j) {
                float4 v = *(float4*)&lds[j * 1028 + tid * 4];
                int ogZ = ot * 8 + p * 4 + j;
                *(float4*)&ZmB[(size_t)ogZ * 4096 + n0 * 8 + tid * 4] = v;
            }
            __syncthreads();
        }
    } else {
        // cand: ogZ = tx; oi = j
        float* ZmB = Z + (size_t)(m * 32 + b) * (16 * 2048);
        #pragma unroll
        for (int p = 0; p < 2; ++p) {
            if ((tx >> 3) == p) {
                int a = tx & 7;
                #pragma unroll
                for (int i = 0; i < 8; ++i)
                    *(float4*)&lds[a * 516 + (ty * 8 + i) * 4] =
                        make_float4(acc[i][0], acc[i][1], acc[i][2], acc[i][3]);
            }
            __syncthreads();
            #pragma unroll
            for (int j = 0; j < 4; ++j) {
                int a = j * 2 + (tid >> 7);
                int q4 = tid & 127;
                float4 v = *(float4*)&lds[a * 516 + q4 * 4];
                int ogZ = p * 8 + a;
                *(float4*)&ZmB[(size_t)ogZ * 2048 + n0 * 4 + q4 * 4] = v;
            }
            __syncthreads();
        }
    }
}

// ---------------- combine: out = Z0 - Z2 - Z4 + S1(Z1+2S1Z2) + S2(Z3+2S2Z4) -----
// HX: Zm's are missing the rank-1 x-term -> add x[b][n] * Wx[m][o] at read time.
// MODE 0: gate -> g = sigmoid(out + bg)        (OO=128, W=8)
// MODE 1: cand -> h = u*h + (1-u)*tanh(out+bc) (OO=64,  W=4), u from gin
template<int MODE, bool HX>
__global__ __launch_bounds__(512) void combine(const float* __restrict__ Z,
                                               const int2* __restrict__ ell,
                                               const int* __restrict__ ecnt,
                                               const float* __restrict__ bias,
                                               const float* __restrict__ xv,
                                               const float* __restrict__ Wx,
                                               float* __restrict__ gout,
                                               const float* __restrict__ gin,
                                               float* __restrict__ h) {
    constexpr int W  = (MODE == 0) ? 8 : 4;
    constexpr int OO = (MODE == 0) ? 128 : 64;
    constexpr size_t TILE = (size_t)512 * W;
    const size_t MS = (size_t)32 * (OO / W) * TILE;   // per-m stride = RTOT*OO

    __shared__ float Ta[512 * W];
    __shared__ float Tb[512 * W];

    int b  = blockIdx.x >> 4;
    int o0 = (blockIdx.x & 15) * W;
    int n  = threadIdx.x;
    const float* Zt = Z + ((size_t)b * (OO / W) + (o0 / W)) * TILE;

    int cnt0 = ecnt[n], cnt1 = ecnt[NN + n];

    float xw[5][W];
    float xn = 0.f;
    if (HX) {
        #pragma unroll
        for (int m = 0; m < 5; ++m)
            #pragma unroll
            for (int fi = 0; fi < W; ++fi)
                xw[m][fi] = Wx[(size_t)m * OO + o0 + fi];
        xn = xv[b * 512 + n];
    }

    auto stage = [&](float* T, int m) {
        const float4* src = (const float4*)(Zt + m * MS);
        if (W == 8) {
            #pragma unroll
            for (int i = 0; i < 2; ++i) {
                int f4 = i * 512 + n;
                int row = f4 >> 1, half = f4 & 1;
                float4 v = src[f4];
                if (HX) {
                    float xr = xv[b * 512 + row];
                    v.x += xr * xw[m][half * 4 + 0]; v.y += xr * xw[m][half * 4 + 1];
                    v.z += xr * xw[m][half * 4 + 2]; v.w += xr * xw[m][half * 4 + 3];
                }
                *(float4*)&T[row * 8 + ((half ^ row) & 1) * 4] = v;
            }
        } else {
            float4 v = src[n];
            if (HX) {
                v.x += xn * xw[m][0]; v.y += xn * xw[m][1];
                v.z += xn * xw[m][2]; v.w += xn * xw[m][3];
            }
            *(float4*)&T[n * 4] = v;
        }
    };
    auto own_lds = [&](const float* T, float* o) {
        if (W == 8) {
            *(float4*)&o[0] = *(const float4*)&T[n * 8 + (n & 1) * 4];
            *(float4*)&o[4] = *(const float4*)&T[n * 8 + ((n & 1) ^ 1) * 4];
        } else {
            *(float4*)&o[0] = *(const float4*)&T[n * 4];
        }
    };
    auto own_glob = [&](int m, float* o) {
        const float* src = Zt + m * MS + (size_t)n * W;
        #pragma unroll
        for (int fi = 0; fi < W; ++fi) {
            o[fi] = src[fi];
            if (HX) o[fi] += xn * xw[m][fi];
        }
    };
    auto put_own = [&](float* T, const float* y) {
        if (W == 8) {
            *(float4*)&T[n * 8 + (n & 1) * 4]       = *(const float4*)&y[0];
            *(float4*)&T[n * 8 + ((n & 1) ^ 1) * 4] = *(const float4*)&y[4];
        } else {
            *(float4*)&T[n * 4] = *(const float4*)&y[0];
        }
    };
    auto gather = [&](const float* T, int s, float* o) {
        int cnt = s ? cnt1 : cnt0;
        const int2* e0 = ell + s * NN + n;
        float4 a0 = make_float4(0.f, 0.f, 0.f, 0.f);
        float4 a1 = make_float4(0.f, 0.f, 0.f, 0.f);
        for (int p = 0; p < cnt; ++p) {
            int2 e = e0[(size_t)p << 10];
            int j = e.x;
            float v = __int_as_float(e.y);
            if (W == 8) {
                float4 x0 = *(const float4*)&T[j * 8 + (j & 1) * 4];
                float4 x1 = *(const float4*)&T[j * 8 + ((j & 1) ^ 1) * 4];
                a0.x += v * x0.x; a0.y += v * x0.y; a0.z += v * x0.z; a0.w += v * x0.w;
                a1.x += v * x1.x; a1.y += v * x1.y; a1.z += v * x1.z; a1.w += v * x1.w;
            } else {
                float4 x0 = *(const float4*)&T[j * 4];
                a0.x += v * x0.x; a0.y += v * x0.y; a0.z += v * x0.z; a0.w += v * x0.w;
            }
        }
        *(float4*)&o[0] = a0;
        if (W == 8) *(float4*)&o[4] = a1;
    };

    float z2own[W], z4own[W], y[W], g2[W], g4[W], t1[W];

    stage(Ta, 2);                       // Z2
    __syncthreads();
    own_lds(Ta, z2own);
    gather(Ta, 0, t1);                  // S1 Z2
    own_glob(1, y);                     // Z1
    #pragma unroll
    for (int fi = 0; fi < W; ++fi) y[fi] += 2.f * t1[fi];
    __syncthreads();
    put_own(Tb, y);
    __syncthreads();
    gather(Tb, 0, g2);                  // S1 (Z1 + 2 S1 Z2)
    __syncthreads();
    stage(Ta, 4);                       // Z4
    own_glob(3, y);                     // Z3
    __syncthreads();
    own_lds(Ta, z4own);
    gather(Ta, 1, t1);                  // S2 Z4
    #pragma unroll
    for (int fi = 0; fi < W; ++fi) y[fi] += 2.f * t1[fi];
    __syncthreads();
    put_own(Tb, y);
    __syncthreads();
    gather(Tb, 1, g4);                  // S2 (Z3 + 2 S2 Z4)
    own_glob(0, t1);                    // Z0

    #pragma unroll
    for (int fi = 0; fi < W; ++fi) {
        float acc = t1[fi] - z2own[fi] - z4own[fi] + g2[fi] + g4[fi] + bias[o0 + fi];
        if (MODE == 0) {
            gout[(size_t)((b << 7) + o0 + fi) * 512 + n] = sigm(acc);
        } else {
            float u  = gin[(size_t)((b << 7) + 64 + o0 + fi) * 512 + n];
            float* hp = &h[(size_t)((b << 6) + o0 + fi) * 512 + n];
            float cv = tanhf(acc);
            *hp = u * (*hp) + (1.f - u) * cv;
        }
    }
}

// ---------------- projection ----------------------------------------------------
__global__ void proj_kernel(const float* __restrict__ h1, const float* __restrict__ pW,
                            const float* __restrict__ pb, float* __restrict__ outt) {
    int r = blockIdx.x * 256 + threadIdx.x;
    if (r >= RTOT) return;
    int b = r >> 9, n = r & 511;
    float acc = pb[0];
    #pragma unroll 16
    for (int u = 0; u < 64; ++u)
        acc += h1[(size_t)((b << 6) + u) * 512 + n] * pW[u];
    outt[b * NN + n] = acc;
}

// ================================================================================
extern "C" void kernel_launch(void* const* d_in, const int* in_sizes, int n_in,
                              void* d_out, int out_size, void* d_ws, size_t ws_size,
                              hipStream_t stream) {
    const float* inputs   = (const float*)d_in[0];
    const float* supports = (const float*)d_in[1];
    const float* enc0_Wg = (const float*)d_in[2];
    const float* enc0_bg = (const float*)d_in[3];
    const float* enc0_Wc = (const float*)d_in[4];
    const float* enc0_bc = (const float*)d_in[5];
    const float* enc1_Wg = (const float*)d_in[6];
    const float* enc1_bg = (const float*)d_in[7];
    const float* enc1_Wc = (const float*)d_in[8];
    const float* enc1_bc = (const float*)d_in[9];
    const float* dec0_Wg = (const float*)d_in[10];
    const float* dec0_bg = (const float*)d_in[11];
    const float* dec0_Wc = (const float*)d_in[12];
    const float* dec0_bc = (const float*)d_in[13];
    const float* dec1_Wg = (const float*)d_in[14];
    const float* dec1_bg = (const float*)d_in[15];
    const float* dec1_Wc = (const float*)d_in[16];
    const float* dec1_bc = (const float*)d_in[17];
    const float* projW   = (const float*)d_in[18];
    const float* projb   = (const float*)d_in[19];
    float* out = (float*)d_out;

    char* wsb = (char*)d_ws;
    size_t off = 0;
    auto alloc = [&](size_t bytes) -> char* {
        char* p = wsb + off;
        off = (off + bytes + 255) & ~(size_t)255;
        return p;
    };
    int2*  ell   = (int2*)alloc((size_t)CAP * 1024 * 8);
    int*   ecnt  = (int*)alloc((size_t)2 * NN * 4);
    float* h0    = (float*)alloc((size_t)RTOT * UU * 4);     // [b][u][n]
    float* h1    = (float*)alloc((size_t)RTOT * UU * 4);
    float* xzero = (float*)alloc((size_t)RTOT * 4);
    float* g     = (float*)alloc((size_t)RTOT * 128 * 4);    // [b][go][n]
    float* Z     = (float*)alloc((size_t)5 * RTOT * 128 * 4);
    if (off > ws_size) return;

    build_ell<<<256, 256, 0, stream>>>(supports, ell, ecnt);
    {
        int nz = RTOT * UU * 2 + RTOT;  // h0, h1, xzero contiguous
        zero_kernel<<<(nz + 255) / 256, 256, 0, stream>>>(h0, nz);
    }

    auto cell_l0 = [&](const float* x_bn, float* h, const float* Wgp, const float* bgp,
                       const float* Wcp, const float* bcp) {
        gemm_f<true, false, 128><<<dim3(128, 5, 2), 256, 0, stream>>>(h, nullptr, nullptr, Wgp, Z);
        combine<0, true><<<512, 512, 0, stream>>>(Z, ell, ecnt, bgp, x_bn, Wgp,
                                                  g, nullptr, nullptr);
        gemm_f<true, true, 64><<<dim3(128, 5, 1), 256, 0, stream>>>(h, nullptr, g, Wcp, Z);
        combine<1, true><<<512, 512, 0, stream>>>(Z, ell, ecnt, bcp, x_bn, Wcp,
                                                  nullptr, g, h);
    };
    auto cell_l1 = [&](const float* hin, float* h, const float* Wgp, const float* bgp,
                       const float* Wcp, const float* bcp) {
        gemm_f<false, false, 128><<<dim3(128, 5, 2), 256, 0, stream>>>(hin, h, nullptr, Wgp, Z);
        combine<0, false><<<512, 512, 0, stream>>>(Z, ell, ecnt, bgp, nullptr, nullptr,
                                                   g, nullptr, nullptr);
        gemm_f<false, true, 64><<<dim3(128, 5, 1), 256, 0, stream>>>(hin, h, g, Wcp, Z);
        combine<1, false><<<512, 512, 0, stream>>>(Z, ell, ecnt, bcp, nullptr, nullptr,
                                                   nullptr, g, h);
    };

    for (int t = 0; t < TT; ++t) {
        cell_l0(inputs + (size_t)t * BB * NN, h0, enc0_Wg, enc0_bg, enc0_Wc, enc0_bc);
        cell_l1(h0, h1, enc1_Wg, enc1_bg, enc1_Wc, enc1_bc);
    }
    for (int t = 0; t < HH; ++t) {
        const float* xin = (t == 0) ? xzero : (out + (size_t)(t - 1) * BB * NN);
        cell_l0(xin, h0, dec0_Wg, dec0_bg, dec0_Wc, dec0_bc);
        cell_l1(h0, h1, dec1_Wg, dec1_bg, dec1_Wc, dec1_bc);
        proj_kernel<<<(RTOT + 255) / 256, 256, 0, stream>>>(h1, projW, projb,
                                                            out + (size_t)t * BB * NN);
    }
}

// Round 9
// 6211.311 us; speedup vs baseline: 1.1030x; 1.0374x over previous
//
#include <hip/hip_runtime.h>
#include <math.h>

#define NN 512
#define BB 32
#define TT 12
#define HH 12
#define UU 64
#define CAP 128
#define RTOT (NN * BB)          // 16384 rows

__device__ __forceinline__ float sigm(float x) { return 1.f / (1.f + expf(-x)); }

// ---------------- ELL build: int2 {idx, val_bits} at [p*1024 + s*512 + row] -----
__global__ __launch_bounds__(256) void build_ell(const float* __restrict__ sup,
                                                 int2* __restrict__ ell,
                                                 int* __restrict__ ecnt) {
    int wave = (blockIdx.x * blockDim.x + threadIdx.x) >> 6;
    int lane = threadIdx.x & 63;
    if (wave >= 2 * NN) return;
    const float* row = sup + (size_t)wave * NN;
    int base = 0;
    for (int k = 0; k < NN / 64; ++k) {
        float v = row[k * 64 + lane];
        unsigned long long m = __ballot(v != 0.0f);
        int pre = __popcll(m & ((1ull << lane) - 1ull));
        if (v != 0.0f) {
            int pos = base + pre;
            if (pos < CAP)
                ell[(size_t)pos * 1024 + wave] = make_int2(k * 64 + lane, __float_as_int(v));
        }
        base += __popcll(m);
    }
    if (lane == 0) ecnt[wave] = base < CAP ? base : CAP;
}

__global__ void zero_kernel(float* __restrict__ p, int n) {
    int i = blockIdx.x * 256 + threadIdx.x;
    if (i < n) p[i] = 0.0f;
}

// ---------------- dense GEMM: Zm = X0_h @ Wm (h-channels only; x via combine) ---
// 128n x 64o tile, 256 threads (thread = 8n x 4o), single-buffer LDS + reg
// prefetch; LDS-transpose epilogue for lane-contiguous Z stores.
// Z layout: gate: Z[m][b][ogZ16][512n][8oi]; cand: Z[m][b][ogZ16][512n][4oi]
template<bool L0, bool GATED, int OO>
__global__ __launch_bounds__(256) void gemm_f(const float* __restrict__ hA,
                                              const float* __restrict__ hB,
                                              const float* __restrict__ g,
                                              const float* __restrict__ W,
                                              float* __restrict__ Z) {
    constexpr int C  = L0 ? 64 : 128;
    constexpr int KT = C / 32;

    __shared__ float At[32][128];   // 16 KB
    __shared__ float Ws[32][68];    // 8.7 KB

    int bx = blockIdx.x;
    int b  = bx >> 2;
    int n0 = (bx & 3) * 128;
    int m  = blockIdx.y;
    int ot = blockIdx.z;                 // o-tile (gate: 0/1, cand: 0)
    int tid = threadIdx.x, tx = tid & 15, ty = tid >> 4;

    float acc[8][4];
    #pragma unroll
    for (int i = 0; i < 8; ++i)
        #pragma unroll
        for (int j = 0; j < 4; ++j) acc[i][j] = 0.f;

    float4 va[4], vw[2];

    auto loadAB = [&](int kt) {
        #pragma unroll
        for (int i = 0; i < 4; ++i) {
            int f4 = i * 256 + tid;
            int c = kt * 32 + (f4 >> 5);
            int nn = n0 + (f4 & 31) * 4;
            float4 v;
            if (L0) {
                v = *(const float4*)&hA[(size_t)((b << 6) + c) * 512 + nn];
                if (GATED) {
                    float4 gv = *(const float4*)&g[(size_t)((b << 7) + c) * 512 + nn];
                    v.x *= gv.x; v.y *= gv.y; v.z *= gv.z; v.w *= gv.w;
                }
            } else {
                if (c < 64) {
                    v = *(const float4*)&hA[(size_t)((b << 6) + c) * 512 + nn];
                } else {
                    int u = c - 64;
                    v = *(const float4*)&hB[(size_t)((b << 6) + u) * 512 + nn];
                    if (GATED) {
                        float4 gv = *(const float4*)&g[(size_t)((b << 7) + u) * 512 + nn];
                        v.x *= gv.x; v.y *= gv.y; v.z *= gv.z; v.w *= gv.w;
                    }
                }
            }
            va[i] = v;
        }
        #pragma unroll
        for (int i = 0; i < 2; ++i) {
            int f4 = i * 256 + tid;
            int kk = f4 >> 4, o4 = f4 & 15;
            int c = kt * 32 + kk;
            int crow = L0 ? (c + 1) : c;      // L0: x occupies original row 0
            vw[i] = *(const float4*)&W[(size_t)(crow * 5 + m) * OO + ot * 64 + o4 * 4];
        }
    };
    auto stash = [&]() {
        #pragma unroll
        for (int i = 0; i < 4; ++i) {
            int f4 = i * 256 + tid;
            *(float4*)&At[f4 >> 5][(f4 & 31) * 4] = va[i];
        }
        #pragma unroll
        for (int i = 0; i < 2; ++i) {
            int f4 = i * 256 + tid;
            *(float4*)&Ws[f4 >> 4][(f4 & 15) * 4] = vw[i];
        }
    };

    loadAB(0);
    for (int kt = 0; kt < KT; ++kt) {
        __syncthreads();
        stash();
        __syncthreads();
        if (kt + 1 < KT) loadAB(kt + 1);
        #pragma unroll 8
        for (int kk = 0; kk < 32; ++kk) {
            float4 a0 = *(float4*)&At[kk][ty * 8];
            float4 a1 = *(float4*)&At[kk][ty * 8 + 4];
            float4 w  = *(float4*)&Ws[kk][tx * 4];
            float av[8] = {a0.x, a0.y, a0.z, a0.w, a1.x, a1.y, a1.z, a1.w};
            #pragma unroll
            for (int i = 0; i < 8; ++i) {
                acc[i][0] += av[i] * w.x; acc[i][1] += av[i] * w.y;
                acc[i][2] += av[i] * w.z; acc[i][3] += av[i] * w.w;
            }
        }
    }
    __syncthreads();

    float* lds = &At[0][0];
    if (OO == 128) {
        float* ZmB = Z + (size_t)(m * 32 + b) * (16 * 4096);
        #pragma unroll
        for (int p = 0; p < 2; ++p) {
            if ((tx >> 3) == p) {
                int a = (tx >> 1) & 3, hi = (tx & 1) * 4;
                #pragma unroll
                for (int i = 0; i < 8; ++i)
                    *(float4*)&lds[a * 1028 + (ty * 8 + i) * 8 + hi] =
                        make_float4(acc[i][0], acc[i][1], acc[i][2], acc[i][3]);
            }
            __syncthreads();
            #pragma unroll
            for (int j = 0; j < 4; ++j) {
                float4 v = *(float4*)&lds[j * 1028 + tid * 4];
                int ogZ = ot * 8 + p * 4 + j;
                *(float4*)&ZmB[(size_t)ogZ * 4096 + n0 * 8 + tid * 4] = v;
            }
            __syncthreads();
        }
    } else {
        float* ZmB = Z + (size_t)(m * 32 + b) * (16 * 2048);
        #pragma unroll
        for (int p = 0; p < 2; ++p) {
            if ((tx >> 3) == p) {
                int a = tx & 7;
                #pragma unroll
                for (int i = 0; i < 8; ++i)
                    *(float4*)&lds[a * 516 + (ty * 8 + i) * 4] =
                        make_float4(acc[i][0], acc[i][1], acc[i][2], acc[i][3]);
            }
            __syncthreads();
            #pragma unroll
            for (int j = 0; j < 4; ++j) {
                int a = j * 2 + (tid >> 7);
                int q4 = tid & 127;
                float4 v = *(float4*)&lds[a * 516 + q4 * 4];
                int ogZ = p * 8 + a;
                *(float4*)&ZmB[(size_t)ogZ * 2048 + n0 * 4 + q4 * 4] = v;
            }
            __syncthreads();
        }
    }
}

// ---------------- combine: out = Z0 - Z2 - Z4 + S1(Z1+2S1Z2) + S2(Z3+2S2Z4) -----
// Restructured: all global loads hoisted; 3 LDS tiles; 3 barriers; both supports'
// hop-1 gathers fused, then both hop-2 gathers fused. FP ops identical to before.
// HX: Zm's are missing the rank-1 x-term -> add x[b][n] * Wx[m][o] at read time.
// MODE 0: gate -> g = sigmoid(out + bg)        (OO=128, W=8)
// MODE 1: cand -> h = u*h + (1-u)*tanh(out+bc) (OO=64,  W=4), u from gin
template<int MODE, bool HX>
__global__ __launch_bounds__(512) void combine(const float* __restrict__ Z,
                                               const int2* __restrict__ ell,
                                               const int* __restrict__ ecnt,
                                               const float* __restrict__ bias,
                                               const float* __restrict__ xv,
                                               const float* __restrict__ Wx,
                                               float* __restrict__ gout,
                                               const float* __restrict__ gin,
                                               float* __restrict__ h) {
    constexpr int W  = (MODE == 0) ? 8 : 4;
    constexpr int OO = (MODE == 0) ? 128 : 64;
    constexpr size_t TILE = (size_t)512 * W;
    const size_t MS = (size_t)32 * (OO / W) * TILE;   // per-m stride = RTOT*OO

    __shared__ float Ta[512 * W];
    __shared__ float Tb[512 * W];
    __shared__ float Tc[512 * W];

    int b  = blockIdx.x >> 4;
    int o0 = (blockIdx.x & 15) * W;
    int n  = threadIdx.x;
    const float* Zt = Z + ((size_t)b * (OO / W) + (o0 / W)) * TILE;

    int cnt0 = ecnt[n], cnt1 = ecnt[NN + n];
    float xn = HX ? xv[b * 512 + n] : 0.f;

    auto xwv = [&](int m, int fi) -> float {   // broadcast weight read (L2-hot)
        return Wx[(size_t)m * OO + o0 + fi];
    };

    // ---- all global loads up front ----
    float4 s2a, s2b, s4a, s4b;
    {
        const float4* src2 = (const float4*)(Zt + 2 * MS);
        const float4* src4 = (const float4*)(Zt + 4 * MS);
        s2a = src2[n]; s4a = src4[n];
        if (W == 8) { s2b = src2[512 + n]; s4b = src4[512 + n]; }
    }
    float y1[W], y2[W], z0own[W], z2own[W], z4own[W], g2[W], g4[W], t1[W];
    auto own_ld = [&](int m, float* o) {
        #pragma unroll
        for (int i = 0; i < W / 4; ++i)
            *(float4*)&o[i * 4] = *(const float4*)(Zt + m * MS + (size_t)n * W + i * 4);
        if (HX) {
            #pragma unroll
            for (int fi = 0; fi < W; ++fi) o[fi] += xn * xwv(m, fi);
        }
    };
    own_ld(1, y1);      // Z1 (+hx)
    own_ld(3, y2);      // Z3 (+hx)
    own_ld(0, z0own);   // Z0 (+hx)
    own_ld(2, z2own);   // Z2 own (+hx) — bitwise equal to staged value
    own_ld(4, z4own);   // Z4 own (+hx)

    float uval[W], hval[W];
    if (MODE == 1) {
        #pragma unroll
        for (int fi = 0; fi < W; ++fi) {
            uval[fi] = gin[(size_t)((b << 7) + 64 + o0 + fi) * 512 + n];
            hval[fi] = h[(size_t)((b << 6) + o0 + fi) * 512 + n];
        }
    }

    // ---- stage Z2 -> Ta, Z4 -> Tc (swizzled, +hx per staged row) ----
    auto stage_st = [&](float* T, int m, float4 a, float4 b4) {
        if (W == 8) {
            {
                int row = n >> 1, half = n & 1;
                if (HX) {
                    float xr = xv[b * 512 + row];
                    a.x += xr * xwv(m, half * 4 + 0); a.y += xr * xwv(m, half * 4 + 1);
                    a.z += xr * xwv(m, half * 4 + 2); a.w += xr * xwv(m, half * 4 + 3);
                }
                *(float4*)&T[row * 8 + ((half ^ row) & 1) * 4] = a;
            }
            {
                int f4 = 512 + n;
                int row = f4 >> 1, half = f4 & 1;
                if (HX) {
                    float xr = xv[b * 512 + row];
                    b4.x += xr * xwv(m, half * 4 + 0); b4.y += xr * xwv(m, half * 4 + 1);
                    b4.z += xr * xwv(m, half * 4 + 2); b4.w += xr * xwv(m, half * 4 + 3);
                }
                *(float4*)&T[row * 8 + ((half ^ row) & 1) * 4] = b4;
            }
        } else {
            if (HX) {
                a.x += xn * xwv(m, 0); a.y += xn * xwv(m, 1);
                a.z += xn * xwv(m, 2); a.w += xn * xwv(m, 3);
            }
            *(float4*)&T[n * 4] = a;
        }
    };
    stage_st(Ta, 2, s2a, s2b);
    stage_st(Tc, 4, s4a, s4b);

    auto put_own = [&](float* T, const float* y) {
        if (W == 8) {
            *(float4*)&T[n * 8 + (n & 1) * 4]       = *(const float4*)&y[0];
            *(float4*)&T[n * 8 + ((n & 1) ^ 1) * 4] = *(const float4*)&y[4];
        } else {
            *(float4*)&T[n * 4] = *(const float4*)&y[0];
        }
    };
    auto gather = [&](const float* T, int s, float* o) {
        int cnt = s ? cnt1 : cnt0;
        const int2* e0 = ell + s * NN + n;
        float4 a0 = make_float4(0.f, 0.f, 0.f, 0.f);
        float4 a1 = make_float4(0.f, 0.f, 0.f, 0.f);
        for (int p = 0; p < cnt; ++p) {
            int2 e = e0[(size_t)p << 10];
            int j = e.x;
            float v = __int_as_float(e.y);
            if (W == 8) {
                float4 x0 = *(const float4*)&T[j * 8 + (j & 1) * 4];
                float4 x1 = *(const float4*)&T[j * 8 + ((j & 1) ^ 1) * 4];
                a0.x += v * x0.x; a0.y += v * x0.y; a0.z += v * x0.z; a0.w += v * x0.w;
                a1.x += v * x1.x; a1.y += v * x1.y; a1.z += v * x1.z; a1.w += v * x1.w;
            } else {
                float4 x0 = *(const float4*)&T[j * 4];
                a0.x += v * x0.x; a0.y += v * x0.y; a0.z += v * x0.z; a0.w += v * x0.w;
            }
        }
        *(float4*)&o[0] = a0;
        if (W == 8) *(float4*)&o[4] = a1;
    };

    __syncthreads();                    // bar 1: tiles staged

    gather(Ta, 0, t1);                  // S1 Z2
    #pragma unroll
    for (int fi = 0; fi < W; ++fi) y1[fi] += 2.f * t1[fi];
    gather(Tc, 1, t1);                  // S2 Z4
    #pragma unroll
    for (int fi = 0; fi < W; ++fi) y2[fi] += 2.f * t1[fi];

    __syncthreads();                    // bar 2: hop-1 reads done, safe to overwrite

    put_own(Tb, y1);
    put_own(Tc, y2);

    __syncthreads();                    // bar 3: y tiles ready

    gather(Tb, 0, g2);                  // S1 (Z1 + 2 S1 Z2)
    gather(Tc, 1, g4);                  // S2 (Z3 + 2 S2 Z4)

    #pragma unroll
    for (int fi = 0; fi < W; ++fi) {
        float acc = z0own[fi] - z2own[fi] - z4own[fi] + g2[fi] + g4[fi] + bias[o0 + fi];
        if (MODE == 0) {
            gout[(size_t)((b << 7) + o0 + fi) * 512 + n] = sigm(acc);
        } else {
            float cv = tanhf(acc);
            h[(size_t)((b << 6) + o0 + fi) * 512 + n] =
                uval[fi] * hval[fi] + (1.f - uval[fi]) * cv;
        }
    }
}

// ---------------- projection ----------------------------------------------------
__global__ void proj_kernel(const float* __restrict__ h1, const float* __restrict__ pW,
                            const float* __restrict__ pb, float* __restrict__ outt) {
    int r = blockIdx.x * 256 + threadIdx.x;
    if (r >= RTOT) return;
    int b = r >> 9, n = r & 511;
    float acc = pb[0];
    #pragma unroll 16
    for (int u = 0; u < 64; ++u)
        acc += h1[(size_t)((b << 6) + u) * 512 + n] * pW[u];
    outt[b * NN + n] = acc;
}

// ================================================================================
extern "C" void kernel_launch(void* const* d_in, const int* in_sizes, int n_in,
                              void* d_out, int out_size, void* d_ws, size_t ws_size,
                              hipStream_t stream) {
    const float* inputs   = (const float*)d_in[0];
    const float* supports = (const float*)d_in[1];
    const float* enc0_Wg = (const float*)d_in[2];
    const float* enc0_bg = (const float*)d_in[3];
    const float* enc0_Wc = (const float*)d_in[4];
    const float* enc0_bc = (const float*)d_in[5];
    const float* enc1_Wg = (const float*)d_in[6];
    const float* enc1_bg = (const float*)d_in[7];
    const float* enc1_Wc = (const float*)d_in[8];
    const float* enc1_bc = (const float*)d_in[9];
    const float* dec0_Wg = (const float*)d_in[10];
    const float* dec0_bg = (const float*)d_in[11];
    const float* dec0_Wc = (const float*)d_in[12];
    const float* dec0_bc = (const float*)d_in[13];
    const float* dec1_Wg = (const float*)d_in[14];
    const float* dec1_bg = (const float*)d_in[15];
    const float* dec1_Wc = (const float*)d_in[16];
    const float* dec1_bc = (const float*)d_in[17];
    const float* projW   = (const float*)d_in[18];
    const float* projb   = (const float*)d_in[19];
    float* out = (float*)d_out;

    char* wsb = (char*)d_ws;
    size_t off = 0;
    auto alloc = [&](size_t bytes) -> char* {
        char* p = wsb + off;
        off = (off + bytes + 255) & ~(size_t)255;
        return p;
    };
    int2*  ell   = (int2*)alloc((size_t)CAP * 1024 * 8);
    int*   ecnt  = (int*)alloc((size_t)2 * NN * 4);
    float* h0    = (float*)alloc((size_t)RTOT * UU * 4);     // [b][u][n]
    float* h1    = (float*)alloc((size_t)RTOT * UU * 4);
    float* xzero = (float*)alloc((size_t)RTOT * 4);
    float* g     = (float*)alloc((size_t)RTOT * 128 * 4);    // [b][go][n]
    float* Z     = (float*)alloc((size_t)5 * RTOT * 128 * 4);
    if (off > ws_size) return;

    build_ell<<<256, 256, 0, stream>>>(supports, ell, ecnt);
    {
        int nz = RTOT * UU * 2 + RTOT;  // h0, h1, xzero contiguous
        zero_kernel<<<(nz + 255) / 256, 256, 0, stream>>>(h0, nz);
    }

    auto cell_l0 = [&](const float* x_bn, float* h, const float* Wgp, const float* bgp,
                       const float* Wcp, const float* bcp) {
        gemm_f<true, false, 128><<<dim3(128, 5, 2), 256, 0, stream>>>(h, nullptr, nullptr, Wgp, Z);
        combine<0, true><<<512, 512, 0, stream>>>(Z, ell, ecnt, bgp, x_bn, Wgp,
                                                  g, nullptr, nullptr);
        gemm_f<true, true, 64><<<dim3(128, 5, 1), 256, 0, stream>>>(h, nullptr, g, Wcp, Z);
        combine<1, true><<<512, 512, 0, stream>>>(Z, ell, ecnt, bcp, x_bn, Wcp,
                                                  nullptr, g, h);
    };
    auto cell_l1 = [&](const float* hin, float* h, const float* Wgp, const float* bgp,
                       const float* Wcp, const float* bcp) {
        gemm_f<false, false, 128><<<dim3(128, 5, 2), 256, 0, stream>>>(hin, h, nullptr, Wgp, Z);
        combine<0, false><<<512, 512, 0, stream>>>(Z, ell, ecnt, bgp, nullptr, nullptr,
                                                   g, nullptr, nullptr);
        gemm_f<false, true, 64><<<dim3(128, 5, 1), 256, 0, stream>>>(hin, h, g, Wcp, Z);
        combine<1, false><<<512, 512, 0, stream>>>(Z, ell, ecnt, bcp, nullptr, nullptr,
                                                   nullptr, g, h);
    };

    for (int t = 0; t < TT; ++t) {
        cell_l0(inputs + (size_t)t * BB * NN, h0, enc0_Wg, enc0_bg, enc0_Wc, enc0_bc);
        cell_l1(h0, h1, enc1_Wg, enc1_bg, enc1_Wc, enc1_bc);
    }
    for (int t = 0; t < HH; ++t) {
        const float* xin = (t == 0) ? xzero : (out + (size_t)(t - 1) * BB * NN);
        cell_l0(xin, h0, dec0_Wg, dec0_bg, dec0_Wc, dec0_bc);
        cell_l1(h0, h1, dec1_Wg, dec1_bg, dec1_Wc, dec1_bc);
        proj_kernel<<<(RTOT + 255) / 256, 256, 0, stream>>>(h1, projW, projb,
                                                            out + (size_t)t * BB * NN);
    }
}